// Round 14
// baseline (466.188 us; speedup 1.0000x reference)
//
#include <hip/hip_runtime.h>
#include <hip/hip_bf16.h>

// Problem constants (fixed by reference)
#define Kn   5
#define Pn   10
#define Hn   256
#define NDn  20
#define OUTn 40
#define INDn 40     // INPUT_DIM
#define ROWn 400    // P * INPUT_DIM
#define TT   64     // t-rows per block (8 waves; halves per-row weight traffic vs TT=32)
#define CSTRIDE 52  // cstage row stride (floats): lg-stride 208/4%32=20 -> 2-way (free)

typedef float  f32x4  __attribute__((ext_vector_type(4)));
typedef float  f32x2  __attribute__((ext_vector_type(2)));
typedef short  bf16x8 __attribute__((ext_vector_type(8)));
typedef unsigned int u32;
typedef unsigned short u16;

// d_ws layout (bf16 element offsets). Per expert e = ke*10+p.
#define W1B_OFF 0
#define W1B_PER 8192        // 1 kstep  x [256][32]
#define W2B_OFF 409600
#define W2B_PER 65536       // 8 ksteps x [256][32]
#define W3B_OFF 3686400
#define W3B_PER 12288       // 8 ksteps x [48][32]
#define WS_ELEMS 4300800
#define WS_BYTES (WS_ELEMS * 2)

__device__ __forceinline__ u16 f2bf(float f) {
    u32 u = __float_as_uint(f);
    return (u16)((u + 0x7fffu + ((u >> 16) & 1u)) >> 16);   // RNE
}

// HW packed f32x2 -> bf16x2 (RNE), 1 VALU op
__device__ __forceinline__ u32 cvt_pk_bf16(float a, float b) {
    u32 r;
    asm("v_cvt_pk_bf16_f32 %0, %1, %2" : "=v"(r) : "v"(a), "v"(b));
    return r;
}

// ---------------- prep: weights -> bf16 fragment layout, AND gating -> cfp ----------------
__global__ void prep_weights(const float* __restrict__ W1, const float* __restrict__ W2,
                             const float* __restrict__ W3, const float* __restrict__ inputs,
                             const float* __restrict__ avoid_p,
                             float* __restrict__ cfp, short* __restrict__ ws, int T) {
    int sid = blockIdx.x * 256 + threadIdx.x;           // one thread = one 16B slot (8 bf16)
    const float* src; int e, kst, n, ss, kmax, ng, nmax; size_t obase;
    if (sid < 51200) {                                   // W1
        e = sid >> 10; int r = sid & 1023; n = r >> 2; ss = r & 3; kst = 0;
        src = W1 + (size_t)e * (NDn * Hn); kmax = NDn; ng = Hn; nmax = Hn;
        obase = W1B_OFF + (size_t)e * W1B_PER;
    } else if (sid < 460800) {                           // W2
        int s = sid - 51200; e = s >> 13; int r = s & 8191;
        kst = r >> 10; int rr = r & 1023; n = rr >> 2; ss = rr & 3;
        src = W2 + (size_t)e * (Hn * Hn); kmax = Hn; ng = Hn; nmax = Hn;
        obase = W2B_OFF + (size_t)e * W2B_PER + (size_t)kst * 8192;
    } else if (sid < 537600) {                           // W3
        int s = sid - 460800; e = s / 1536; int r = s - e * 1536;
        kst = r / 192; int rr = r - kst * 192; n = rr >> 2; ss = rr & 3;
        src = W3 + (size_t)e * (Hn * OUTn); kmax = Hn; ng = OUTn; nmax = OUTn;
        obase = W3B_OFF + (size_t)e * W3B_PER + (size_t)kst * 1536;
    } else {                                             // gating -> cfp (T*90 items)
        int g = sid - 537600;
        if (g < T * (Pn * (Pn - 1))) {
            int t = g / 90, rm = g - t * 90;
            int pp = rm / 9, j = rm - pp * 9;
            size_t base = ((size_t)t * Kn + (Kn - 1)) * ROWn + pp * INDn;
            float xF  = inputs[base + 31 + j];
            float xF2 = inputs[base + 22 + j];
            float s1 = 1.0f / (1.0f + __expf(-100.0f * (xF - *avoid_p)));
            float s2 = 1.0f / (1.0f + __expf(-100.0f * xF2));
            cfp[g] = s1 * (s2 - 0.5f) * 2.0f;
        }
        return;
    }

    u16 v[8];
    #pragma unroll
    for (int j = 0; j < 8; ++j) {
        int k = kst * 32 + ss * 8 + j;
        float f = (k < kmax && n < nmax) ? src[(size_t)k * ng + n] : 0.0f;
        v[j] = f2bf(f);
    }
    u32 q0 = (u32)v[0] | ((u32)v[1] << 16), q1 = (u32)v[2] | ((u32)v[3] << 16);
    u32 q2 = (u32)v[4] | ((u32)v[5] << 16), q3 = (u32)v[6] | ((u32)v[7] << 16);
    *(uint4*)(ws + obase + (size_t)n * 32 + ss * 8) = make_uint4(q0, q1, q2, q3);
}

// epilogue: relu (bias already in acc), per-lane b16 store into hA [t][k] (XOR-swizzled).
// Bank-check: 16 lanes (lr) span 32B contiguous -> 2 lanes/bank = conflict-free.
__device__ __forceinline__ void epi_store_h(short* hA_, const f32x4 (*A)[4],
                                            int mh, int nq, int lane) {
    const int lg = lane >> 4, lr = lane & 15;
    #pragma unroll
    for (int mt = 0; mt < 2; ++mt) {
        #pragma unroll
        for (int r = 0; r < 4; ++r) {
            const int t = 32 * mh + 16 * mt + 4 * lg + r;
            #pragma unroll
            for (int nt = 0; nt < 4; ++nt) {
                float vv = fmaxf(A[mt][nt][r], 0.0f);
                u32 pk = cvt_pk_bf16(vv, vv);
                int col = 64 * nq + 16 * nt + lr;
                int off = t * 512 + ((2 * col) ^ ((t & 7) << 4));
                *reinterpret_cast<u16*>(reinterpret_cast<char*>(hA_) + off) = (u16)pk;
            }
        }
    }
}

// phase C K-step: compute KS from cur; prefetch KS+1 into nxt
template<int KS>
__device__ __forceinline__ void c_step(const char* w2, const short* hA_, int mh, int nq,
                                       int lg, int lr, bf16x8 (&cur)[4], bf16x8 (&nxt)[4],
                                       f32x4 (&acc)[2][4]) {
    if (KS < 7) {
        #pragma unroll
        for (int nt = 0; nt < 4; ++nt) {
            int n = 64 * nq + 16 * nt + lr;
            nxt[nt] = *(const bf16x8*)(w2 + (KS + 1) * 16384 + n * 64 + lg * 16);
        }
    }
    bf16x8 aF[2];
    #pragma unroll
    for (int mt = 0; mt < 2; ++mt) {
        int t = 32 * mh + 16 * mt + lr;
        aF[mt] = *(const bf16x8*)((const char*)hA_ + t * 512 + ((KS * 64 + lg * 16) ^ ((t & 7) << 4)));
    }
    #pragma unroll
    for (int mt = 0; mt < 2; ++mt)
        #pragma unroll
        for (int nt = 0; nt < 4; ++nt)
            acc[mt][nt] = __builtin_amdgcn_mfma_f32_16x16x32_bf16(aF[mt], cur[nt], acc[mt][nt], 0, 0, 0);
}

// phase D K-step
template<int KS>
__device__ __forceinline__ void d_step(const char* w3, const short* hA_, int t, int ncnt,
                                       int nbase, int lg, int lr,
                                       bf16x8 (&cur)[2], bf16x8 (&nxt)[2], f32x4 (&accd)[2]) {
    if (KS < 7) {
        #pragma unroll
        for (int j = 0; j < 2; ++j)
            if (j < ncnt) {
                int n = 16 * (nbase + j) + lr;
                nxt[j] = *(const bf16x8*)(w3 + (KS + 1) * 3072 + n * 64 + lg * 16);
            }
    }
    bf16x8 aF = *(const bf16x8*)((const char*)hA_ + t * 512 + ((KS * 64 + lg * 16) ^ ((t & 7) << 4)));
    #pragma unroll
    for (int j = 0; j < 2; ++j)
        if (j < ncnt)
            accd[j] = __builtin_amdgcn_mfma_f32_16x16x32_bf16(aF, cur[j], accd[j], 0, 0, 0);
}

// ---------------- main fused kernel: one (ke,p,chunk64) per 512-thread block ----------------
// launch_bounds(512,4): VGPR cap 64 -> 4 blocks/CU (LDS 38.9KB also -> 4) = 32 waves/CU.
__launch_bounds__(512, 4)
__global__ void senngc_mfma(const float* __restrict__ inputs,
                            const float* __restrict__ b1, const float* __restrict__ b2,
                            const float* __restrict__ b3,
                            const float* __restrict__ cfp_in,
                            const short* __restrict__ ws,
                            float* __restrict__ preds, float* __restrict__ coeffs, int T)
{
    __shared__ __align__(16) short selA[TT * 32];    // 4KB
    __shared__ __align__(16) short hA[TT * Hn];      // 32KB; reused as fp32 cstage [64][CSTRIDE]
    __shared__ u16  sh_mult[TT][NDn];                // 2.5KB

    const int tid  = threadIdx.x;

    // bijective XCD-chunked swizzle over (pair=(p,ke), chunk)
    const int NB   = gridDim.x;
    const int nch  = NB / (Pn * Kn);                 // t-chunks per (p,ke) pair
    const int bx   = blockIdx.x & 7, bj = blockIdx.x >> 3;
    const int bbase = NB >> 3, brem = NB & 7;
    const int L    = bx * bbase + (bx < brem ? bx : brem) + bj;
    const int pair = L / nch;
    const int t0   = (L - pair * nch) * TT;
    const int p    = pair / Kn;
    const int ke   = pair - p * Kn;

    const int wid  = tid >> 6, lane = tid & 63;
    const int lg   = lane >> 4, lr = lane & 15;
    const int mh   = wid >> 2, nq = wid & 3;         // B/C wave tile: rows 32*mh, cols 64*nq

    const int e = ke * Pn + p;
    const char* w1 = (const char*)(ws + W1B_OFF + (size_t)e * W1B_PER);
    const char* w2 = (const char*)(ws + W2B_OFF + (size_t)e * W2B_PER);
    const char* w3 = (const char*)(ws + W3B_OFF + (size_t)e * W3B_PER);

    // ---- phase A (loads first: these gate barrier b1) ----
    // sel gather, vectorized: 4x float2 per thread; pad k>=NDn zeroed (k is the
    // reduction axis); out-of-range rows are row-clamped (masked later at phase E)
    if (tid < 256) {
        int row = tid >> 2, ss = tid & 3;
        int kg = ss ^ ((row >> 1) & 3);
        int trow = (t0 + row < T) ? (t0 + row) : (T - 1);
        const float* src = inputs + ((size_t)trow * Kn + ke) * ROWn + p * INDn;
        int c0 = kg ? (kg * 8 + 2) : 0;
        int o1 = kg ? (c0 + 2) : 4;
        int o2 = kg ? (c0 + 4) : 6;
        int o3 = kg ? (c0 + 6) : 8;
        f32x2 va = *(const f32x2*)(src + c0);
        f32x2 vb = *(const f32x2*)(src + o1);
        f32x2 vc = *(const f32x2*)(src + o2);
        f32x2 vd = *(const f32x2*)(src + o3);
        float f[8] = {va[0], va[1], vb[0], vb[1], vc[0], vc[1], vd[0], vd[1]};
        #pragma unroll
        for (int j = 0; j < 8; ++j)
            if (kg * 8 + j >= NDn) f[j] = 0.0f;
        u32 q0 = cvt_pk_bf16(f[0], f[1]), q1 = cvt_pk_bf16(f[2], f[3]);
        u32 q2 = cvt_pk_bf16(f[4], f[5]), q3 = cvt_pk_bf16(f[6], f[7]);
        *(uint4*)((char*)selA + row * 64 + ss * 16) = make_uint4(q0, q1, q2, q3);
    }

    // gating read-back from cfp (precomputed in prep) -> sh_mult; 576 items, 2 passes
    if (tid < TT) *(u32*)&sh_mult[tid][0] = 0x3F803F80u;   // mult[:,0:2] = 1.0
    {
        int r = tid / 9, j = tid - r * 9;
        if (tid < TT * (Pn - 1)) {                         // all 512 threads
            float cf = (t0 + r < T) ? cfp_in[(size_t)(t0 + r) * (Pn * (Pn - 1)) + p * (Pn - 1) + j] : 0.0f;
            *(u32*)&sh_mult[r][2 + 2 * j] = cvt_pk_bf16(cf, cf);
        }
        int i2 = tid + 512;
        if (i2 < TT * (Pn - 1)) {                          // tid < 64
            int r2 = i2 / 9, j2 = i2 - r2 * 9;
            float cf = (t0 + r2 < T) ? cfp_in[(size_t)(t0 + r2) * (Pn * (Pn - 1)) + p * (Pn - 1) + j2] : 0.0f;
            *(u32*)&sh_mult[r2][2 + 2 * j2] = cvt_pk_bf16(cf, cf);
        }
    }

    // W1 fragment loads + biases (L2-hot; folded into acc init, not epilogue)
    bf16x8 bW[4];
    float bias1[4], bias2[4];
    #pragma unroll
    for (int nt = 0; nt < 4; ++nt) {
        int n = 64 * nq + 16 * nt + lr;
        bW[nt] = *(const bf16x8*)(w1 + n * 64 + lg * 16);
        bias1[nt] = b1[e * Hn + n];
        bias2[nt] = b2[e * Hn + n];
    }
    __syncthreads();                               // b1: selA/sh_mult visible

    f32x4 acc[2][4];

    // ---- phase B: h1 = relu(selA @ W1 + b1), K=32 (padded from 20); bias in acc init ----
    #pragma unroll
    for (int mt = 0; mt < 2; ++mt)
        #pragma unroll
        for (int nt = 0; nt < 4; ++nt)
            acc[mt][nt] = (f32x4){bias1[nt], bias1[nt], bias1[nt], bias1[nt]};
    {
        bf16x8 aS[2];
        #pragma unroll
        for (int mt = 0; mt < 2; ++mt) {
            int t = 32 * mh + 16 * mt + lr;
            aS[mt] = *(const bf16x8*)((const char*)selA + t * 64 + ((lg ^ ((t >> 1) & 3)) << 4));
        }
        #pragma unroll
        for (int mt = 0; mt < 2; ++mt)
            #pragma unroll
            for (int nt = 0; nt < 4; ++nt)
                acc[mt][nt] = __builtin_amdgcn_mfma_f32_16x16x32_bf16(aS[mt], bW[nt], acc[mt][nt], 0, 0, 0);
    }
    // issue C-phase kstep-0 B loads NOW (latency hidden under epilogue+barrier)
    bf16x8 bA[4], bB[4];
    #pragma unroll
    for (int nt = 0; nt < 4; ++nt) {
        int n = 64 * nq + 16 * nt + lr;
        bA[nt] = *(const bf16x8*)(w2 + n * 64 + lg * 16);
    }
    epi_store_h(hA, acc, mh, nq, lane);
    __syncthreads();                               // b2: h1 visible

    // ---- phase C: h2 = relu(h1 @ W2 + b2), K=256, 1-deep reg prefetch, NO barriers ----
    #pragma unroll
    for (int mt = 0; mt < 2; ++mt)
        #pragma unroll
        for (int nt = 0; nt < 4; ++nt)
            acc[mt][nt] = (f32x4){bias2[nt], bias2[nt], bias2[nt], bias2[nt]};
    c_step<0>(w2, hA, mh, nq, lg, lr, bA, bB, acc);
    c_step<1>(w2, hA, mh, nq, lg, lr, bB, bA, acc);
    c_step<2>(w2, hA, mh, nq, lg, lr, bA, bB, acc);
    c_step<3>(w2, hA, mh, nq, lg, lr, bB, bA, acc);
    c_step<4>(w2, hA, mh, nq, lg, lr, bA, bB, acc);
    c_step<5>(w2, hA, mh, nq, lg, lr, bB, bA, acc);
    c_step<6>(w2, hA, mh, nq, lg, lr, bA, bB, acc);
    c_step<7>(w2, hA, mh, nq, lg, lr, bB, bA, acc);
    __syncthreads();                               // b3: all C reads of hA done

    // D geometry: wave-pair per 16-row slot (mslot 0..3); even wave n-tiles {0,1}, odd {2}
    const int mslot = wid >> 1;
    const int nbase = (wid & 1) ? 2 : 0;
    const int ncnt  = (wid & 1) ? 1 : 2;
    const int tD    = 16 * mslot + lr;
    bf16x8 dA[2], dB[2];
    #pragma unroll
    for (int j = 0; j < 2; ++j)
        if (j < ncnt) {
            int n = 16 * (nbase + j) + lr;
            dA[j] = *(const bf16x8*)(w3 + n * 64 + lg * 16);
        }
    epi_store_h(hA, acc, mh, nq, lane);
    __syncthreads();                               // b4: h2 visible

    // ---- phase D: c = h2 @ W3, K=256, N=48 (padded from 40), NO barriers ----
    {
        f32x4 accd[2];
        accd[0] = (f32x4){0.f, 0.f, 0.f, 0.f};
        accd[1] = (f32x4){0.f, 0.f, 0.f, 0.f};
        d_step<0>(w3, hA, tD, ncnt, nbase, lg, lr, dA, dB, accd);
        d_step<1>(w3, hA, tD, ncnt, nbase, lg, lr, dB, dA, accd);
        d_step<2>(w3, hA, tD, ncnt, nbase, lg, lr, dA, dB, accd);
        d_step<3>(w3, hA, tD, ncnt, nbase, lg, lr, dB, dA, accd);
        d_step<4>(w3, hA, tD, ncnt, nbase, lg, lr, dA, dB, accd);
        d_step<5>(w3, hA, tD, ncnt, nbase, lg, lr, dB, dA, accd);
        d_step<6>(w3, hA, tD, ncnt, nbase, lg, lr, dA, dB, accd);
        d_step<7>(w3, hA, tD, ncnt, nbase, lg, lr, dB, dA, accd);
        __syncthreads();                           // b5: all D reads of hA done
        {   // cstage (fp32, stride CSTRIDE) overlays hA
            float* cst = (float*)hA;
            #pragma unroll
            for (int j = 0; j < 2; ++j)
                if (j < ncnt)
                    #pragma unroll
                    for (int r = 0; r < 4; ++r)
                        cst[(16 * mslot + 4 * lg + r) * CSTRIDE + 16 * (nbase + j) + lr] = accd[j][r];
        }
    }
    __syncthreads();                               // b6: cstage visible

    // ---- phase E: single pass (512 threads = 64 rows x 8 groups); register accum +
    //      4-lane shfl reduce; NO LDS atomics ----
    {
        const float* cst = (const float*)hA;
        const int r  = tid >> 3, g = tid & 7;      // r 0..63
        const int d  = g >> 2;
        const int o0 = 5 * g;
        const int n0 = 5 * (g & 3);
        float s = 0.0f;
        if (t0 + r < T) {
            const float* bb3 = b3 + e * OUTn + o0;
            float* crow = coeffs + (((size_t)(t0 + r) * Kn + ke) * Pn + p) * OUTn + o0;
            #pragma unroll
            for (int j = 0; j < 5; ++j) {
                float c = cst[r * CSTRIDE + o0 + j] + bb3[j];
                int n = n0 + j;
                float m = __uint_as_float((u32)sh_mult[r][n] << 16);
                float c2 = c * c * m;
                crow[j] = c2;
                int offs = r * 64 + (((n >> 3) ^ ((r >> 1) & 3)) << 4) + (n & 7) * 2;
                u16 u = *(const u16*)((const char*)selA + offs);
                s = fmaf(c2, __uint_as_float((u32)u << 16), s);
            }
        }
        s += __shfl_xor(s, 1);
        s += __shfl_xor(s, 2);
        // cross-block k-reduction (preds zeroed by hipMemsetAsync)
        if ((g & 3) == 0 && t0 + r < T)
            atomicAdd(&preds[(size_t)(t0 + r) * (Pn * 2) + p * 2 + d], s);
    }
}

// ---------------- fp32 fallback (round-1 kernel, TT=32) ----------------
#define FMA4(ACC, A, W)              \
    ACC.x = fmaf(A.x, W, ACC.x);     \
    ACC.y = fmaf(A.y, W, ACC.y);     \
    ACC.z = fmaf(A.z, W, ACC.z);     \
    ACC.w = fmaf(A.w, W, ACC.w);

__launch_bounds__(256, 4)
__global__ void senngc_fused_f32(const float* __restrict__ inputs,
                                 const float* __restrict__ W1, const float* __restrict__ b1,
                                 const float* __restrict__ W2, const float* __restrict__ b2,
                                 const float* __restrict__ W3, const float* __restrict__ b3,
                                 const float* __restrict__ avoid_p,
                                 float* __restrict__ preds, float* __restrict__ coeffs,
                                 float* __restrict__ cfp, int T)
{
    __shared__ __align__(16) float lds_T[Hn * 32];
    __shared__ __align__(16) float selT[NDn * 32];
    __shared__ float sh_mult[32][NDn];
    __shared__ float sh_pred[32][2];

    const int tid = threadIdx.x;
    const int p   = blockIdx.y;
    const int t0  = blockIdx.x * 32;
    const float avoid = *avoid_p;

    if (tid < 64) {
        sh_pred[tid >> 1][tid & 1] = 0.0f;
        sh_mult[tid >> 1][tid & 1] = 1.0f;
    }
    for (int i = tid; i < 32 * (Pn - 1); i += 256) {
        int r = i / 9, j = i - r * 9;
        float cf = 0.0f;
        if (t0 + r < T) {
            size_t base = ((size_t)(t0 + r) * Kn + (Kn - 1)) * ROWn + p * INDn;
            float xF  = inputs[base + 31 + j];
            float xF2 = inputs[base + 22 + j];
            float s1 = 1.0f / (1.0f + __expf(-100.0f * (xF - avoid)));
            float s2 = 1.0f / (1.0f + __expf(-100.0f * xF2));
            cf = s1 * (s2 - 0.5f) * 2.0f;
            cfp[(size_t)(t0 + r) * (Pn * (Pn - 1)) + p * (Pn - 1) + j] = cf;
        }
        sh_mult[r][2 + 2 * j] = cf;
        sh_mult[r][3 + 2 * j] = cf;
    }

    const int tr = tid >> 5;
    const int tc = tid & 31;
    float4 acc[8];

    for (int k = 0; k < Kn; ++k) {
        __syncthreads();
        for (int i = tid; i < NDn * 32; i += 256) {
            int n = i >> 5, r = i & 31;
            float v = 0.0f;
            if (t0 + r < T) {
                int col = p * INDn + (n < 2 ? n : n + 2);
                v = inputs[((size_t)(t0 + r) * Kn + k) * ROWn + col];
            }
            selT[n * 32 + r] = v;
        }
        __syncthreads();
        {
            const float* w1 = W1 + (size_t)(k * Pn + p) * NDn * Hn;
            const float* bb = b1 + (k * Pn + p) * Hn;
            float4 bv0 = *(const float4*)(bb + 8 * tc);
            float4 bv1 = *(const float4*)(bb + 8 * tc + 4);
            acc[0] = make_float4(bv0.x, bv0.x, bv0.x, bv0.x);
            acc[1] = make_float4(bv0.y, bv0.y, bv0.y, bv0.y);
            acc[2] = make_float4(bv0.z, bv0.z, bv0.z, bv0.z);
            acc[3] = make_float4(bv0.w, bv0.w, bv0.w, bv0.w);
            acc[4] = make_float4(bv1.x, bv1.x, bv1.x, bv1.x);
            acc[5] = make_float4(bv1.y, bv1.y, bv1.y, bv1.y);
            acc[6] = make_float4(bv1.z, bv1.z, bv1.z, bv1.z);
            acc[7] = make_float4(bv1.w, bv1.w, bv1.w, bv1.w);
            #pragma unroll 4
            for (int kk = 0; kk < NDn; ++kk) {
                float4 a = *(const float4*)&selT[kk * 32 + 4 * tr];
                const float* wr = w1 + kk * Hn + 8 * tc;
                float4 w0  = *(const float4*)(wr);
                float4 w1v = *(const float4*)(wr + 4);
                FMA4(acc[0], a, w0.x);  FMA4(acc[1], a, w0.y);
                FMA4(acc[2], a, w0.z);  FMA4(acc[3], a, w0.w);
                FMA4(acc[4], a, w1v.x); FMA4(acc[5], a, w1v.y);
                FMA4(acc[6], a, w1v.z); FMA4(acc[7], a, w1v.w);
            }
            #pragma unroll
            for (int c = 0; c < 8; ++c) {
                int col = 8 * tc + c;
                float4 v = acc[c];
                v.x = fmaxf(v.x, 0.0f); v.y = fmaxf(v.y, 0.0f);
                v.z = fmaxf(v.z, 0.0f); v.w = fmaxf(v.w, 0.0f);
                *(float4*)&lds_T[col * 32 + ((4 * tr) ^ ((col & 7) << 2))] = v;
            }
        }
        __syncthreads();
        {
            const float* w2 = W2 + (size_t)(k * Pn + p) * Hn * Hn;
            const float* bb = b2 + (k * Pn + p) * Hn;
            float4 bv0 = *(const float4*)(bb + 8 * tc);
            float4 bv1 = *(const float4*)(bb + 8 * tc + 4);
            acc[0] = make_float4(bv0.x, bv0.x, bv0.x, bv0.x);
            acc[1] = make_float4(bv0.y, bv0.y, bv0.y, bv0.y);
            acc[2] = make_float4(bv0.z, bv0.z, bv0.z, bv0.z);
            acc[3] = make_float4(bv0.w, bv0.w, bv0.w, bv0.w);
            acc[4] = make_float4(bv1.x, bv1.x, bv1.x, bv1.x);
            acc[5] = make_float4(bv1.y, bv1.y, bv1.y, bv1.y);
            acc[6] = make_float4(bv1.z, bv1.z, bv1.z, bv1.z);
            acc[7] = make_float4(bv1.w, bv1.w, bv1.w, bv1.w);
            #pragma unroll 2
            for (int kk = 0; kk < Hn; ++kk) {
                float4 a = *(const float4*)&lds_T[kk * 32 + ((4 * tr) ^ ((kk & 7) << 2))];
                const float* wr = w2 + kk * Hn + 8 * tc;
                float4 w0  = *(const float4*)(wr);
                float4 w1v = *(const float4*)(wr + 4);
                FMA4(acc[0], a, w0.x);  FMA4(acc[1], a, w0.y);
                FMA4(acc[2], a, w0.z);  FMA4(acc[3], a, w0.w);
                FMA4(acc[4], a, w1v.x); FMA4(acc[5], a, w1v.y);
                FMA4(acc[6], a, w1v.z); FMA4(acc[7], a, w1v.w);
            }
            __syncthreads();
            #pragma unroll
            for (int c = 0; c < 8; ++c) {
                int col = 8 * tc + c;
                float4 v = acc[c];
                v.x = fmaxf(v.x, 0.0f); v.y = fmaxf(v.y, 0.0f);
                v.z = fmaxf(v.z, 0.0f); v.w = fmaxf(v.w, 0.0f);
                *(float4*)&lds_T[col * 32 + ((4 * tr) ^ ((col & 7) << 2))] = v;
            }
        }
        __syncthreads();
        {
            const int kq  = tid >> 6;
            const int tr2 = (tid >> 3) & 7;
            const int cg  = tid & 7;
            const float* w3 = W3 + (size_t)(k * Pn + p) * Hn * OUTn;
            float accd[4][5];
            #pragma unroll
            for (int a_ = 0; a_ < 4; ++a_)
                #pragma unroll
                for (int j = 0; j < 5; ++j) accd[a_][j] = 0.0f;
            #pragma unroll 2
            for (int kk = kq * 64; kk < kq * 64 + 64; ++kk) {
                float4 a = *(const float4*)&lds_T[kk * 32 + ((4 * tr2) ^ ((kk & 7) << 2))];
                const float* wr = w3 + kk * OUTn + 5 * cg;
                #pragma unroll
                for (int j = 0; j < 5; ++j) {
                    float w = wr[j];
                    accd[0][j] = fmaf(a.x, w, accd[0][j]);
                    accd[1][j] = fmaf(a.y, w, accd[1][j]);
                    accd[2][j] = fmaf(a.z, w, accd[2][j]);
                    accd[3][j] = fmaf(a.w, w, accd[3][j]);
                }
            }
            __syncthreads();
            #pragma unroll
            for (int r4 = 0; r4 < 4; ++r4)
                #pragma unroll
                for (int j = 0; j < 5; ++j)
                    lds_T[(kq * 32 + 4 * tr2 + r4) * OUTn + 5 * cg + j] = accd[r4][j];
        }
        __syncthreads();
        {
            const float* bb3 = b3 + (k * Pn + p) * OUTn;
            for (int i = tid; i < 32 * OUTn; i += 256) {
                int r = i / OUTn, o = i - r * OUTn;
                if (t0 + r >= T) continue;
                float c = bb3[o]
                        + lds_T[(0 * 32 + r) * OUTn + o]
                        + lds_T[(1 * 32 + r) * OUTn + o]
                        + lds_T[(2 * 32 + r) * OUTn + o]
                        + lds_T[(3 * 32 + r) * OUTn + o];
                int d = (o >= NDn) ? 1 : 0;
                int n = o - d * NDn;
                float c2 = c * c * sh_mult[r][n];
                coeffs[(((size_t)(t0 + r) * Kn + k) * Pn + p) * OUTn + o] = c2;
                atomicAdd(&sh_pred[r][d], c2 * selT[n * 32 + r]);
            }
        }
    }

    __syncthreads();
    if (tid < 64) {
        int r = tid >> 1, d = tid & 1;
        if (t0 + r < T)
            preds[(size_t)(t0 + r) * (Pn * 2) + p * 2 + d] = sh_pred[r][d];
    }
}

extern "C" void kernel_launch(void* const* d_in, const int* in_sizes, int n_in,
                              void* d_out, int out_size, void* d_ws, size_t ws_size,
                              hipStream_t stream) {
    const float* inputs = (const float*)d_in[0];
    const float* W1 = (const float*)d_in[1];
    const float* b1 = (const float*)d_in[2];
    const float* W2 = (const float*)d_in[3];
    const float* b2 = (const float*)d_in[4];
    const float* W3 = (const float*)d_in[5];
    const float* b3 = (const float*)d_in[6];
    const float* avoid = (const float*)d_in[7];
    const int T = in_sizes[0] / (Kn * ROWn);

    float* out    = (float*)d_out;
    float* preds  = out;                                   // (T, 20)
    float* coeffs = out + (size_t)T * (Pn * 2);            // (T, K, P*2, 20)
    float* cfp    = coeffs + (size_t)T * Kn * Pn * OUTn;   // (T, P, 9)

    if (ws_size >= (size_t)WS_BYTES) {
        short* ws = (short*)d_ws;
        hipMemsetAsync(preds, 0, (size_t)T * (Pn * 2) * sizeof(float), stream);
        const int prep_items = 537600 + T * (Pn * (Pn - 1));
        hipLaunchKernelGGL(prep_weights, dim3((prep_items + 255) / 256), dim3(256), 0, stream,
                           W1, W2, W3, inputs, avoid, cfp, ws, T);
        const int nch = (T + TT - 1) / TT;                 // 313
        hipLaunchKernelGGL(senngc_mfma, dim3(nch * Pn * Kn), dim3(512), 0, stream,
                           inputs, b1, b2, b3, cfp, ws, preds, coeffs, T);
    } else {
        dim3 grid((T + 31) / 32, Pn);
        hipLaunchKernelGGL(senngc_fused_f32, grid, dim3(256), 0, stream,
                           inputs, W1, b1, W2, b2, W3, b3, avoid, preds, coeffs, cfp, T);
    }
}

// Round 15
// 432.883 us; speedup vs baseline: 1.0769x; 1.0769x over previous
//
#include <hip/hip_runtime.h>
#include <hip/hip_bf16.h>

// Problem constants (fixed by reference)
#define Kn   5
#define Pn   10
#define Hn   256
#define NDn  20
#define OUTn 40
#define INDn 40     // INPUT_DIM
#define ROWn 400    // P * INPUT_DIM
#define TT   32     // t-rows per block (small block -> 8 independent blocks/CU)
#define CSTRIDE 52  // cstage row stride (floats)

typedef float  f32x4  __attribute__((ext_vector_type(4)));
typedef float  f32x2  __attribute__((ext_vector_type(2)));
typedef short  bf16x8 __attribute__((ext_vector_type(8)));
typedef unsigned int u32;
typedef unsigned short u16;

// d_ws layout (bf16 element offsets). Per expert e = ke*10+p.
#define W1B_OFF 0
#define W1B_PER 8192        // 1 kstep  x [256][32]
#define W2B_OFF 409600
#define W2B_PER 65536       // 8 ksteps x [256][32]
#define W3B_OFF 3686400
#define W3B_PER 12288       // 8 ksteps x [48][32]
#define WS_ELEMS 4300800
#define WS_BYTES (WS_ELEMS * 2)

__device__ __forceinline__ u16 f2bf(float f) {
    u32 u = __float_as_uint(f);
    return (u16)((u + 0x7fffu + ((u >> 16) & 1u)) >> 16);   // RNE
}

// HW packed f32x2 -> bf16x2 (RNE), 1 VALU op
__device__ __forceinline__ u32 cvt_pk_bf16(float a, float b) {
    u32 r;
    asm("v_cvt_pk_bf16_f32 %0, %1, %2" : "=v"(r) : "v"(a), "v"(b));
    return r;
}

// ---------------- prep: weights -> bf16 fragment layout, AND gating -> cfp ----------------
__global__ void prep_weights(const float* __restrict__ W1, const float* __restrict__ W2,
                             const float* __restrict__ W3, const float* __restrict__ inputs,
                             const float* __restrict__ avoid_p,
                             float* __restrict__ cfp, short* __restrict__ ws, int T) {
    int sid = blockIdx.x * 256 + threadIdx.x;           // one thread = one 16B slot (8 bf16)
    const float* src; int e, kst, n, ss, kmax, ng, nmax; size_t obase;
    if (sid < 51200) {                                   // W1
        e = sid >> 10; int r = sid & 1023; n = r >> 2; ss = r & 3; kst = 0;
        src = W1 + (size_t)e * (NDn * Hn); kmax = NDn; ng = Hn; nmax = Hn;
        obase = W1B_OFF + (size_t)e * W1B_PER;
    } else if (sid < 460800) {                           // W2
        int s = sid - 51200; e = s >> 13; int r = s & 8191;
        kst = r >> 10; int rr = r & 1023; n = rr >> 2; ss = rr & 3;
        src = W2 + (size_t)e * (Hn * Hn); kmax = Hn; ng = Hn; nmax = Hn;
        obase = W2B_OFF + (size_t)e * W2B_PER + (size_t)kst * 8192;
    } else if (sid < 537600) {                           // W3
        int s = sid - 460800; e = s / 1536; int r = s - e * 1536;
        kst = r / 192; int rr = r - kst * 192; n = rr >> 2; ss = rr & 3;
        src = W3 + (size_t)e * (Hn * OUTn); kmax = Hn; ng = OUTn; nmax = OUTn;
        obase = W3B_OFF + (size_t)e * W3B_PER + (size_t)kst * 1536;
    } else {                                             // gating -> cfp (T*90 items)
        int g = sid - 537600;
        if (g < T * (Pn * (Pn - 1))) {
            int t = g / 90, rm = g - t * 90;
            int pp = rm / 9, j = rm - pp * 9;
            size_t base = ((size_t)t * Kn + (Kn - 1)) * ROWn + pp * INDn;
            float xF  = inputs[base + 31 + j];
            float xF2 = inputs[base + 22 + j];
            float s1 = 1.0f / (1.0f + __expf(-100.0f * (xF - *avoid_p)));
            float s2 = 1.0f / (1.0f + __expf(-100.0f * xF2));
            cfp[g] = s1 * (s2 - 0.5f) * 2.0f;
        }
        return;
    }

    u16 v[8];
    #pragma unroll
    for (int j = 0; j < 8; ++j) {
        int k = kst * 32 + ss * 8 + j;
        float f = (k < kmax && n < nmax) ? src[(size_t)k * ng + n] : 0.0f;
        v[j] = f2bf(f);
    }
    u32 q0 = (u32)v[0] | ((u32)v[1] << 16), q1 = (u32)v[2] | ((u32)v[3] << 16);
    u32 q2 = (u32)v[4] | ((u32)v[5] << 16), q3 = (u32)v[6] | ((u32)v[7] << 16);
    *(uint4*)(ws + obase + (size_t)n * 32 + ss * 8) = make_uint4(q0, q1, q2, q3);
}

// epilogue: relu (bias already in acc), per-lane b16 store into hA [t][k] (XOR-swizzled).
// Bank-check: 16 lanes (lr) span 32B contiguous -> 2 lanes/bank = conflict-free.
__device__ __forceinline__ void epi_store_h(short* hA_, const f32x4 (*A)[4],
                                            int wid, int lane) {
    const int lg = lane >> 4, lr = lane & 15;
    #pragma unroll
    for (int mt = 0; mt < 2; ++mt) {
        #pragma unroll
        for (int r = 0; r < 4; ++r) {
            const int t = 16 * mt + 4 * lg + r;
            #pragma unroll
            for (int nt = 0; nt < 4; ++nt) {
                float vv = fmaxf(A[mt][nt][r], 0.0f);
                u32 pk = cvt_pk_bf16(vv, vv);
                int col = 64 * wid + 16 * nt + lr;
                int off = t * 512 + ((2 * col) ^ ((t & 7) << 4));
                *reinterpret_cast<u16*>(reinterpret_cast<char*>(hA_) + off) = (u16)pk;
            }
        }
    }
}

// phase C K-step: compute KS from cur; prefetch KS+1 into nxt.
// T5: setprio(1) around the MFMA cluster -- CU hosts ~8 independent blocks at
// staggered phases, so prio gives MFMA-entering waves arbitration priority.
template<int KS>
__device__ __forceinline__ void c_step(const char* w2, const short* hA_, int wid,
                                       int lg, int lr, bf16x8 (&cur)[4], bf16x8 (&nxt)[4],
                                       f32x4 (&acc)[2][4]) {
    if (KS < 7) {
        #pragma unroll
        for (int nt = 0; nt < 4; ++nt) {
            int n = 64 * wid + 16 * nt + lr;
            nxt[nt] = *(const bf16x8*)(w2 + (KS + 1) * 16384 + n * 64 + lg * 16);
        }
    }
    bf16x8 aF[2];
    #pragma unroll
    for (int mt = 0; mt < 2; ++mt) {
        int t = 16 * mt + lr;
        aF[mt] = *(const bf16x8*)((const char*)hA_ + t * 512 + ((KS * 64 + lg * 16) ^ ((t & 7) << 4)));
    }
    __builtin_amdgcn_s_setprio(1);
    #pragma unroll
    for (int mt = 0; mt < 2; ++mt)
        #pragma unroll
        for (int nt = 0; nt < 4; ++nt)
            acc[mt][nt] = __builtin_amdgcn_mfma_f32_16x16x32_bf16(aF[mt], cur[nt], acc[mt][nt], 0, 0, 0);
    __builtin_amdgcn_s_setprio(0);
}

// phase D K-step
template<int KS>
__device__ __forceinline__ void d_step(const char* w3, const short* hA_, int t, int ncnt,
                                       int nbase, int lg, int lr,
                                       bf16x8 (&cur)[2], bf16x8 (&nxt)[2], f32x4 (&accd)[2]) {
    if (KS < 7) {
        #pragma unroll
        for (int j = 0; j < 2; ++j)
            if (j < ncnt) {
                int n = 16 * (nbase + j) + lr;
                nxt[j] = *(const bf16x8*)(w3 + (KS + 1) * 3072 + n * 64 + lg * 16);
            }
    }
    bf16x8 aF = *(const bf16x8*)((const char*)hA_ + t * 512 + ((KS * 64 + lg * 16) ^ ((t & 7) << 4)));
    __builtin_amdgcn_s_setprio(1);
    #pragma unroll
    for (int j = 0; j < 2; ++j)
        if (j < ncnt)
            accd[j] = __builtin_amdgcn_mfma_f32_16x16x32_bf16(aF, cur[j], accd[j], 0, 0, 0);
    __builtin_amdgcn_s_setprio(0);
}

// ---------------- main fused kernel: one (ke,p,chunk32) per 256-thread block ----------------
__launch_bounds__(256, 4)
__global__ void senngc_mfma(const float* __restrict__ inputs,
                            const float* __restrict__ b1, const float* __restrict__ b2,
                            const float* __restrict__ b3,
                            const float* __restrict__ cfp_in,
                            const short* __restrict__ ws,
                            float* __restrict__ preds, float* __restrict__ coeffs, int T)
{
    __shared__ __align__(16) short selA[TT * 32];    // 2KB
    __shared__ __align__(16) short hA[TT * Hn];      // 16KB; reused as fp32 cstage [32][CSTRIDE]
    __shared__ u16  sh_mult[TT][NDn];                // 1.25KB

    const int tid  = threadIdx.x;

    // bijective XCD-chunked swizzle over (pair=(p,ke), chunk)
    const int NB   = gridDim.x;
    const int nch  = NB / (Pn * Kn);                 // t-chunks per (p,ke) pair
    const int bx   = blockIdx.x & 7, bj = blockIdx.x >> 3;
    const int bbase = NB >> 3, brem = NB & 7;
    const int L    = bx * bbase + (bx < brem ? bx : brem) + bj;
    const int pair = L / nch;
    const int t0   = (L - pair * nch) * TT;
    const int p    = pair / Kn;
    const int ke   = pair - p * Kn;

    const int wid  = tid >> 6, lane = tid & 63;
    const int lg   = lane >> 4, lr = lane & 15;

    const int e = ke * Pn + p;
    const char* w1 = (const char*)(ws + W1B_OFF + (size_t)e * W1B_PER);
    const char* w2 = (const char*)(ws + W2B_OFF + (size_t)e * W2B_PER);
    const char* w3 = (const char*)(ws + W3B_OFF + (size_t)e * W3B_PER);

    // ---- phase A (loads first: these gate barrier b1) ----
    if (tid < 128) {
        int row = tid >> 2, ss = tid & 3;
        int kg = ss ^ ((row >> 1) & 3);
        int trow = (t0 + row < T) ? (t0 + row) : (T - 1);
        const float* src = inputs + ((size_t)trow * Kn + ke) * ROWn + p * INDn;
        int c0 = kg ? (kg * 8 + 2) : 0;
        int o1 = kg ? (c0 + 2) : 4;
        int o2 = kg ? (c0 + 4) : 6;
        int o3 = kg ? (c0 + 6) : 8;
        f32x2 va = *(const f32x2*)(src + c0);
        f32x2 vb = *(const f32x2*)(src + o1);
        f32x2 vc = *(const f32x2*)(src + o2);
        f32x2 vd = *(const f32x2*)(src + o3);
        float f[8] = {va[0], va[1], vb[0], vb[1], vc[0], vc[1], vd[0], vd[1]};
        #pragma unroll
        for (int j = 0; j < 8; ++j)
            if (kg * 8 + j >= NDn) f[j] = 0.0f;
        u32 q0 = cvt_pk_bf16(f[0], f[1]), q1 = cvt_pk_bf16(f[2], f[3]);
        u32 q2 = cvt_pk_bf16(f[4], f[5]), q3 = cvt_pk_bf16(f[6], f[7]);
        *(uint4*)((char*)selA + row * 64 + ss * 16) = make_uint4(q0, q1, q2, q3);
    }

    // gating read-back from cfp (precomputed in prep) -> sh_mult; manually unrolled
    if (tid < 32) *(u32*)&sh_mult[tid][0] = 0x3F803F80u;   // mult[:,0:2] = 1.0
    {
        int r = tid / 9, j = tid - r * 9;
        if (tid < TT * (Pn - 1)) {
            float cf = (t0 + r < T) ? cfp_in[(size_t)(t0 + r) * (Pn * (Pn - 1)) + p * (Pn - 1) + j] : 0.0f;
            *(u32*)&sh_mult[r][2 + 2 * j] = cvt_pk_bf16(cf, cf);
        }
        int i2 = tid + 256;
        if (i2 < TT * (Pn - 1)) {                          // tid < 32
            int r2 = i2 / 9, j2 = i2 - r2 * 9;
            float cf = (t0 + r2 < T) ? cfp_in[(size_t)(t0 + r2) * (Pn * (Pn - 1)) + p * (Pn - 1) + j2] : 0.0f;
            *(u32*)&sh_mult[r2][2 + 2 * j2] = cvt_pk_bf16(cf, cf);
        }
    }

    // W1 fragment loads + biases (L2-hot; folded into acc init, not epilogue)
    bf16x8 bW[4];
    float bias1[4], bias2[4];
    #pragma unroll
    for (int nt = 0; nt < 4; ++nt) {
        int n = 64 * wid + 16 * nt + lr;
        bW[nt] = *(const bf16x8*)(w1 + n * 64 + lg * 16);
        bias1[nt] = b1[e * Hn + n];
        bias2[nt] = b2[e * Hn + n];
    }
    __syncthreads();                               // b1: selA/sh_mult visible

    f32x4 acc[2][4];

    // ---- phase B: h1 = relu(selA @ W1 + b1), K=32 (padded from 20); bias in acc init ----
    #pragma unroll
    for (int mt = 0; mt < 2; ++mt)
        #pragma unroll
        for (int nt = 0; nt < 4; ++nt)
            acc[mt][nt] = (f32x4){bias1[nt], bias1[nt], bias1[nt], bias1[nt]};
    {
        bf16x8 aS[2];
        #pragma unroll
        for (int mt = 0; mt < 2; ++mt) {
            int t = 16 * mt + lr;
            aS[mt] = *(const bf16x8*)((const char*)selA + t * 64 + ((lg ^ ((t >> 1) & 3)) << 4));
        }
        __builtin_amdgcn_s_setprio(1);
        #pragma unroll
        for (int mt = 0; mt < 2; ++mt)
            #pragma unroll
            for (int nt = 0; nt < 4; ++nt)
                acc[mt][nt] = __builtin_amdgcn_mfma_f32_16x16x32_bf16(aS[mt], bW[nt], acc[mt][nt], 0, 0, 0);
        __builtin_amdgcn_s_setprio(0);
    }
    // issue C-phase kstep-0 B loads NOW (latency hidden under epilogue+barrier)
    bf16x8 bA[4], bB[4];
    #pragma unroll
    for (int nt = 0; nt < 4; ++nt) {
        int n = 64 * wid + 16 * nt + lr;
        bA[nt] = *(const bf16x8*)(w2 + n * 64 + lg * 16);
    }
    epi_store_h(hA, acc, wid, lane);
    __syncthreads();                               // b2: h1 visible

    // ---- phase C: h2 = relu(h1 @ W2 + b2), K=256, 1-deep reg prefetch, NO barriers ----
    #pragma unroll
    for (int mt = 0; mt < 2; ++mt)
        #pragma unroll
        for (int nt = 0; nt < 4; ++nt)
            acc[mt][nt] = (f32x4){bias2[nt], bias2[nt], bias2[nt], bias2[nt]};
    c_step<0>(w2, hA, wid, lg, lr, bA, bB, acc);
    c_step<1>(w2, hA, wid, lg, lr, bB, bA, acc);
    c_step<2>(w2, hA, wid, lg, lr, bA, bB, acc);
    c_step<3>(w2, hA, wid, lg, lr, bB, bA, acc);
    c_step<4>(w2, hA, wid, lg, lr, bA, bB, acc);
    c_step<5>(w2, hA, wid, lg, lr, bB, bA, acc);
    c_step<6>(w2, hA, wid, lg, lr, bA, bB, acc);
    c_step<7>(w2, hA, wid, lg, lr, bB, bA, acc);
    __syncthreads();                               // b3: all C reads of hA done

    // D geometry: wave-pair per 16-row slot; even wave n-tiles {0,1}, odd {2}
    const int mslot = wid >> 1;                    // 0..1
    const int nbase = (wid & 1) ? 2 : 0;
    const int ncnt  = (wid & 1) ? 1 : 2;
    const int tD    = 16 * mslot + lr;
    bf16x8 dA[2], dB[2];
    #pragma unroll
    for (int j = 0; j < 2; ++j)
        if (j < ncnt) {
            int n = 16 * (nbase + j) + lr;
            dA[j] = *(const bf16x8*)(w3 + n * 64 + lg * 16);
        }
    epi_store_h(hA, acc, wid, lane);
    __syncthreads();                               // b4: h2 visible

    // ---- phase D: c = h2 @ W3, K=256, N=48 (padded from 40), NO barriers ----
    {
        f32x4 accd[2];
        accd[0] = (f32x4){0.f, 0.f, 0.f, 0.f};
        accd[1] = (f32x4){0.f, 0.f, 0.f, 0.f};
        d_step<0>(w3, hA, tD, ncnt, nbase, lg, lr, dA, dB, accd);
        d_step<1>(w3, hA, tD, ncnt, nbase, lg, lr, dB, dA, accd);
        d_step<2>(w3, hA, tD, ncnt, nbase, lg, lr, dA, dB, accd);
        d_step<3>(w3, hA, tD, ncnt, nbase, lg, lr, dB, dA, accd);
        d_step<4>(w3, hA, tD, ncnt, nbase, lg, lr, dA, dB, accd);
        d_step<5>(w3, hA, tD, ncnt, nbase, lg, lr, dB, dA, accd);
        d_step<6>(w3, hA, tD, ncnt, nbase, lg, lr, dA, dB, accd);
        d_step<7>(w3, hA, tD, ncnt, nbase, lg, lr, dB, dA, accd);
        __syncthreads();                           // b5: all D reads of hA done
        {   // cstage (fp32, stride CSTRIDE) overlays hA
            float* cst = (float*)hA;
            #pragma unroll
            for (int j = 0; j < 2; ++j)
                if (j < ncnt)
                    #pragma unroll
                    for (int r = 0; r < 4; ++r)
                        cst[(16 * mslot + 4 * lg + r) * CSTRIDE + 16 * (nbase + j) + lr] = accd[j][r];
        }
    }
    __syncthreads();                               // b6: cstage visible

    // ---- phase E: square, gate, coeffs; preds via register accum + 4-lane shfl reduce ----
    {
        const float* cst = (const float*)hA;
        const int r  = tid >> 3, g = tid & 7;
        const int d  = g >> 2;
        const int o0 = 5 * g;
        const int n0 = 5 * (g & 3);
        float s = 0.0f;
        if (t0 + r < T) {
            const float* bb3 = b3 + e * OUTn + o0;
            float* crow = coeffs + (((size_t)(t0 + r) * Kn + ke) * Pn + p) * OUTn + o0;
            #pragma unroll
            for (int j = 0; j < 5; ++j) {
                float c = cst[r * CSTRIDE + o0 + j] + bb3[j];
                int n = n0 + j;
                float m = __uint_as_float((u32)sh_mult[r][n] << 16);
                float c2 = c * c * m;
                crow[j] = c2;
                int offs = r * 64 + (((n >> 3) ^ ((r >> 1) & 3)) << 4) + (n & 7) * 2;
                u16 u = *(const u16*)((const char*)selA + offs);
                s = fmaf(c2, __uint_as_float((u32)u << 16), s);
            }
        }
        s += __shfl_xor(s, 1);
        s += __shfl_xor(s, 2);
        // cross-block k-reduction (preds zeroed by hipMemsetAsync)
        if ((g & 3) == 0 && t0 + r < T)
            atomicAdd(&preds[(size_t)(t0 + r) * (Pn * 2) + p * 2 + d], s);
    }
}

// ---------------- fp32 fallback (round-1 kernel, TT=32) ----------------
#define FMA4(ACC, A, W)              \
    ACC.x = fmaf(A.x, W, ACC.x);     \
    ACC.y = fmaf(A.y, W, ACC.y);     \
    ACC.z = fmaf(A.z, W, ACC.z);     \
    ACC.w = fmaf(A.w, W, ACC.w);

__launch_bounds__(256, 4)
__global__ void senngc_fused_f32(const float* __restrict__ inputs,
                                 const float* __restrict__ W1, const float* __restrict__ b1,
                                 const float* __restrict__ W2, const float* __restrict__ b2,
                                 const float* __restrict__ W3, const float* __restrict__ b3,
                                 const float* __restrict__ avoid_p,
                                 float* __restrict__ preds, float* __restrict__ coeffs,
                                 float* __restrict__ cfp, int T)
{
    __shared__ __align__(16) float lds_T[Hn * 32];
    __shared__ __align__(16) float selT[NDn * 32];
    __shared__ float sh_mult[32][NDn];
    __shared__ float sh_pred[32][2];

    const int tid = threadIdx.x;
    const int p   = blockIdx.y;
    const int t0  = blockIdx.x * 32;
    const float avoid = *avoid_p;

    if (tid < 64) {
        sh_pred[tid >> 1][tid & 1] = 0.0f;
        sh_mult[tid >> 1][tid & 1] = 1.0f;
    }
    for (int i = tid; i < 32 * (Pn - 1); i += 256) {
        int r = i / 9, j = i - r * 9;
        float cf = 0.0f;
        if (t0 + r < T) {
            size_t base = ((size_t)(t0 + r) * Kn + (Kn - 1)) * ROWn + p * INDn;
            float xF  = inputs[base + 31 + j];
            float xF2 = inputs[base + 22 + j];
            float s1 = 1.0f / (1.0f + __expf(-100.0f * (xF - avoid)));
            float s2 = 1.0f / (1.0f + __expf(-100.0f * xF2));
            cf = s1 * (s2 - 0.5f) * 2.0f;
            cfp[(size_t)(t0 + r) * (Pn * (Pn - 1)) + p * (Pn - 1) + j] = cf;
        }
        sh_mult[r][2 + 2 * j] = cf;
        sh_mult[r][3 + 2 * j] = cf;
    }

    const int tr = tid >> 5;
    const int tc = tid & 31;
    float4 acc[8];

    for (int k = 0; k < Kn; ++k) {
        __syncthreads();
        for (int i = tid; i < NDn * 32; i += 256) {
            int n = i >> 5, r = i & 31;
            float v = 0.0f;
            if (t0 + r < T) {
                int col = p * INDn + (n < 2 ? n : n + 2);
                v = inputs[((size_t)(t0 + r) * Kn + k) * ROWn + col];
            }
            selT[n * 32 + r] = v;
        }
        __syncthreads();
        {
            const float* w1 = W1 + (size_t)(k * Pn + p) * NDn * Hn;
            const float* bb = b1 + (k * Pn + p) * Hn;
            float4 bv0 = *(const float4*)(bb + 8 * tc);
            float4 bv1 = *(const float4*)(bb + 8 * tc + 4);
            acc[0] = make_float4(bv0.x, bv0.x, bv0.x, bv0.x);
            acc[1] = make_float4(bv0.y, bv0.y, bv0.y, bv0.y);
            acc[2] = make_float4(bv0.z, bv0.z, bv0.z, bv0.z);
            acc[3] = make_float4(bv0.w, bv0.w, bv0.w, bv0.w);
            acc[4] = make_float4(bv1.x, bv1.x, bv1.x, bv1.x);
            acc[5] = make_float4(bv1.y, bv1.y, bv1.y, bv1.y);
            acc[6] = make_float4(bv1.z, bv1.z, bv1.z, bv1.z);
            acc[7] = make_float4(bv1.w, bv1.w, bv1.w, bv1.w);
            #pragma unroll 4
            for (int kk = 0; kk < NDn; ++kk) {
                float4 a = *(const float4*)&selT[kk * 32 + 4 * tr];
                const float* wr = w1 + kk * Hn + 8 * tc;
                float4 w0  = *(const float4*)(wr);
                float4 w1v = *(const float4*)(wr + 4);
                FMA4(acc[0], a, w0.x);  FMA4(acc[1], a, w0.y);
                FMA4(acc[2], a, w0.z);  FMA4(acc[3], a, w0.w);
                FMA4(acc[4], a, w1v.x); FMA4(acc[5], a, w1v.y);
                FMA4(acc[6], a, w1v.z); FMA4(acc[7], a, w1v.w);
            }
            #pragma unroll
            for (int c = 0; c < 8; ++c) {
                int col = 8 * tc + c;
                float4 v = acc[c];
                v.x = fmaxf(v.x, 0.0f); v.y = fmaxf(v.y, 0.0f);
                v.z = fmaxf(v.z, 0.0f); v.w = fmaxf(v.w, 0.0f);
                *(float4*)&lds_T[col * 32 + ((4 * tr) ^ ((col & 7) << 2))] = v;
            }
        }
        __syncthreads();
        {
            const float* w2 = W2 + (size_t)(k * Pn + p) * Hn * Hn;
            const float* bb = b2 + (k * Pn + p) * Hn;
            float4 bv0 = *(const float4*)(bb + 8 * tc);
            float4 bv1 = *(const float4*)(bb + 8 * tc + 4);
            acc[0] = make_float4(bv0.x, bv0.x, bv0.x, bv0.x);
            acc[1] = make_float4(bv0.y, bv0.y, bv0.y, bv0.y);
            acc[2] = make_float4(bv0.z, bv0.z, bv0.z, bv0.z);
            acc[3] = make_float4(bv0.w, bv0.w, bv0.w, bv0.w);
            acc[4] = make_float4(bv1.x, bv1.x, bv1.x, bv1.x);
            acc[5] = make_float4(bv1.y, bv1.y, bv1.y, bv1.y);
            acc[6] = make_float4(bv1.z, bv1.z, bv1.z, bv1.z);
            acc[7] = make_float4(bv1.w, bv1.w, bv1.w, bv1.w);
            #pragma unroll 2
            for (int kk = 0; kk < Hn; ++kk) {
                float4 a = *(const float4*)&lds_T[kk * 32 + ((4 * tr) ^ ((kk & 7) << 2))];
                const float* wr = w2 + kk * Hn + 8 * tc;
                float4 w0  = *(const float4*)(wr);
                float4 w1v = *(const float4*)(wr + 4);
                FMA4(acc[0], a, w0.x);  FMA4(acc[1], a, w0.y);
                FMA4(acc[2], a, w0.z);  FMA4(acc[3], a, w0.w);
                FMA4(acc[4], a, w1v.x); FMA4(acc[5], a, w1v.y);
                FMA4(acc[6], a, w1v.z); FMA4(acc[7], a, w1v.w);
            }
            __syncthreads();
            #pragma unroll
            for (int c = 0; c < 8; ++c) {
                int col = 8 * tc + c;
                float4 v = acc[c];
                v.x = fmaxf(v.x, 0.0f); v.y = fmaxf(v.y, 0.0f);
                v.z = fmaxf(v.z, 0.0f); v.w = fmaxf(v.w, 0.0f);
                *(float4*)&lds_T[col * 32 + ((4 * tr) ^ ((col & 7) << 2))] = v;
            }
        }
        __syncthreads();
        {
            const int kq  = tid >> 6;
            const int tr2 = (tid >> 3) & 7;
            const int cg  = tid & 7;
            const float* w3 = W3 + (size_t)(k * Pn + p) * Hn * OUTn;
            float accd[4][5];
            #pragma unroll
            for (int a_ = 0; a_ < 4; ++a_)
                #pragma unroll
                for (int j = 0; j < 5; ++j) accd[a_][j] = 0.0f;
            #pragma unroll 2
            for (int kk = kq * 64; kk < kq * 64 + 64; ++kk) {
                float4 a = *(const float4*)&lds_T[kk * 32 + ((4 * tr2) ^ ((kk & 7) << 2))];
                const float* wr = w3 + kk * OUTn + 5 * cg;
                #pragma unroll
                for (int j = 0; j < 5; ++j) {
                    float w = wr[j];
                    accd[0][j] = fmaf(a.x, w, accd[0][j]);
                    accd[1][j] = fmaf(a.y, w, accd[1][j]);
                    accd[2][j] = fmaf(a.z, w, accd[2][j]);
                    accd[3][j] = fmaf(a.w, w, accd[3][j]);
                }
            }
            __syncthreads();
            #pragma unroll
            for (int r4 = 0; r4 < 4; ++r4)
                #pragma unroll
                for (int j = 0; j < 5; ++j)
                    lds_T[(kq * 32 + 4 * tr2 + r4) * OUTn + 5 * cg + j] = accd[r4][j];
        }
        __syncthreads();
        {
            const float* bb3 = b3 + (k * Pn + p) * OUTn;
            for (int i = tid; i < 32 * OUTn; i += 256) {
                int r = i / OUTn, o = i - r * OUTn;
                if (t0 + r >= T) continue;
                float c = bb3[o]
                        + lds_T[(0 * 32 + r) * OUTn + o]
                        + lds_T[(1 * 32 + r) * OUTn + o]
                        + lds_T[(2 * 32 + r) * OUTn + o]
                        + lds_T[(3 * 32 + r) * OUTn + o];
                int d = (o >= NDn) ? 1 : 0;
                int n = o - d * NDn;
                float c2 = c * c * sh_mult[r][n];
                coeffs[(((size_t)(t0 + r) * Kn + k) * Pn + p) * OUTn + o] = c2;
                atomicAdd(&sh_pred[r][d], c2 * selT[n * 32 + r]);
            }
        }
    }

    __syncthreads();
    if (tid < 64) {
        int r = tid >> 1, d = tid & 1;
        if (t0 + r < T)
            preds[(size_t)(t0 + r) * (Pn * 2) + p * 2 + d] = sh_pred[r][d];
    }
}

extern "C" void kernel_launch(void* const* d_in, const int* in_sizes, int n_in,
                              void* d_out, int out_size, void* d_ws, size_t ws_size,
                              hipStream_t stream) {
    const float* inputs = (const float*)d_in[0];
    const float* W1 = (const float*)d_in[1];
    const float* b1 = (const float*)d_in[2];
    const float* W2 = (const float*)d_in[3];
    const float* b2 = (const float*)d_in[4];
    const float* W3 = (const float*)d_in[5];
    const float* b3 = (const float*)d_in[6];
    const float* avoid = (const float*)d_in[7];
    const int T = in_sizes[0] / (Kn * ROWn);

    float* out    = (float*)d_out;
    float* preds  = out;                                   // (T, 20)
    float* coeffs = out + (size_t)T * (Pn * 2);            // (T, K, P*2, 20)
    float* cfp    = coeffs + (size_t)T * Kn * Pn * OUTn;   // (T, P, 9)

    if (ws_size >= (size_t)WS_BYTES) {
        short* ws = (short*)d_ws;
        hipMemsetAsync(preds, 0, (size_t)T * (Pn * 2) * sizeof(float), stream);
        const int prep_items = 537600 + T * (Pn * (Pn - 1));
        hipLaunchKernelGGL(prep_weights, dim3((prep_items + 255) / 256), dim3(256), 0, stream,
                           W1, W2, W3, inputs, avoid, cfp, ws, T);
        const int nch = (T + TT - 1) / TT;                 // 625
        hipLaunchKernelGGL(senngc_mfma, dim3(nch * Pn * Kn), dim3(256), 0, stream,
                           inputs, b1, b2, b3, cfp, ws, preds, coeffs, T);
    } else {
        dim3 grid((T + 31) / 32, Pn);
        hipLaunchKernelGGL(senngc_fused_f32, grid, dim3(256), 0, stream,
                           inputs, W1, b1, W2, b2, W3, b3, avoid, preds, coeffs, cfp, T);
    }
}